// Round 1
// baseline (68.488 us; speedup 1.0000x reference)
//
#include <hip/hip_runtime.h>

#define NRES  300
#define NTRJ  20
#define NBINS 34
#define NTILES 5        // ceil(300/64)
#define PLANE (NTRJ * NRES * 3)   // 18000 floats per output tensor

__device__ __forceinline__ float wred(float v) {
#pragma unroll
  for (int m = 32; m; m >>= 1) v += __shfl_xor(v, m, 64);
  return v;
}

__global__ __launch_bounds__(64)
void force_kernel(const float* __restrict__ cO,
                  const float* __restrict__ cCB,
                  const float* __restrict__ cH,
                  const float* __restrict__ gw,
                  const float* __restrict__ hmin,
                  const float* __restrict__ hmax,
                  float* __restrict__ out) {
  float* accO  = out + 2 * PLANE;
  float* accCB = out + 3 * PLANE;
  float* accH  = out + 4 * PLANE;
  const int lane = threadIdx.x;
  int bx = blockIdx.x;
  const int NCOL = NRES * NTILES * 2;   // 3000 column blocks

  if (bx < NCOL) {
    // ---- column part: fixed j, lanes over i; produces accs_CB[b,j], accs_O[b,j]
    const int j    = bx % NRES;
    const int tile = (bx / NRES) % NTILES;
    const int bh   = bx / (NRES * NTILES);   // 0 or 1 -> which half of trajectories
    const int i    = tile * 64 + lane;
    const bool valid = (i < NRES);
    const int ic   = valid ? i : NRES - 1;

    // per-pair gaussian weights: loaded once, reused for 10 trajectories
    float w[NBINS];
    const float* gp = gw + ((size_t)ic * NRES + j) * NBINS;
#pragma unroll
    for (int k = 0; k < NBINS; ++k) w[k] = gp[k];

    const float hmn = hmin[ic * NRES + j];
    const float hmx = hmax[ic * NRES + j];

    for (int b = bh * (NTRJ / 2); b < (bh + 1) * (NTRJ / 2); ++b) {
      // CB distogram force
      const float* pi = cCB + ((size_t)b * NRES + ic) * 3;
      const float* pj = cCB + ((size_t)b * NRES + j) * 3;
      float dx = pj[0] - pi[0], dy = pj[1] - pi[1], dz = pj[2] - pi[2];
      float d2 = fmaf(dx, dx, fmaf(dy, dy, dz * dz));
      float d  = sqrtf(fmaxf(d2, 1e-12f));
      d = fminf(fmaxf(d, 0.1f), 40.0f);
      float invd = 1.0f / d;
      float s = 0.0f;
#pragma unroll
      for (int k = 0; k < NBINS; ++k) {
        float dfm = d - (3.75f + 0.5f * (float)k);
        float t = dfm * 0.8f;              // dfm / sigma, sigma=1.25
        float e = __expf(-0.5f * t * t);
        s = fmaf(w[k] * dfm, e, s);
      }
      // pair_cb = (150 / sigma^3) * S * diff/d ; 150/1.953125 = 76.8
      float cf = 76.8f * s * invd;
      float px = cf * dx, py = cf * dy, pz = cf * dz;

      // HB min/max restraint (O_j - H_i)
      const float* ph = cH + ((size_t)b * NRES + ic) * 3;
      const float* po = cO + ((size_t)b * NRES + j) * 3;
      float ex = po[0] - ph[0], ey = po[1] - ph[1], ez = po[2] - ph[2];
      float e2 = fmaf(ex, ex, fmaf(ey, ey, ez * ez));
      float dh = sqrtf(fmaxf(e2, 1e-12f));
      dh = fminf(fmaxf(dh, 0.1f), 40.0f);
      float vmin = fmaxf(hmn - dh, 0.0f);
      float vmax = fmaxf(dh - hmx, 0.0f);
      float fmn = 15.0f * vmin;                                   // 3 * 5 * v^1
      float fmx = (vmax > 0.0f) ? 5.0f * __powf(vmax, 0.75f) : 0.0f;
      float ff = (fmn - fmx) / dh;
      float qx = ff * ex, qy = ff * ey, qz = ff * ez;

      if (!valid) { px = py = pz = qx = qy = qz = 0.0f; }

      px = wred(px); py = wred(py); pz = wred(pz);
      qx = wred(qx); qy = wred(qy); qz = wred(qz);
      if (lane == 0) {
        int base = (b * NRES + j) * 3;
        atomicAdd(&accCB[base + 0], px);
        atomicAdd(&accCB[base + 1], py);
        atomicAdd(&accCB[base + 2], pz);
        atomicAdd(&accO[base + 0], qx);
        atomicAdd(&accO[base + 1], qy);
        atomicAdd(&accO[base + 2], qz);
      }
    }
  } else {
    // ---- row part: fixed i, lanes over j; produces accs_H[b,i] = -sum_j pair_hb
    bx -= NCOL;
    const int i    = bx % NRES;
    const int tile = bx / NRES;          // 0..4
    const int j    = tile * 64 + lane;
    const bool valid = (j < NRES);
    const int jc   = valid ? j : NRES - 1;

    const float hmn = hmin[i * NRES + jc];
    const float hmx = hmax[i * NRES + jc];

    for (int b = 0; b < NTRJ; ++b) {
      const float* ph = cH + ((size_t)b * NRES + i) * 3;
      const float* po = cO + ((size_t)b * NRES + jc) * 3;
      float ex = po[0] - ph[0], ey = po[1] - ph[1], ez = po[2] - ph[2];
      float e2 = fmaf(ex, ex, fmaf(ey, ey, ez * ez));
      float dh = sqrtf(fmaxf(e2, 1e-12f));
      dh = fminf(fmaxf(dh, 0.1f), 40.0f);
      float vmin = fmaxf(hmn - dh, 0.0f);
      float vmax = fmaxf(dh - hmx, 0.0f);
      float fmn = 15.0f * vmin;
      float fmx = (vmax > 0.0f) ? 5.0f * __powf(vmax, 0.75f) : 0.0f;
      float ff = (fmn - fmx) / dh;
      float qx = -ff * ex, qy = -ff * ey, qz = -ff * ez;

      if (!valid) { qx = qy = qz = 0.0f; }

      qx = wred(qx); qy = wred(qy); qz = wred(qz);
      if (lane == 0) {
        int base = (b * NRES + i) * 3;
        atomicAdd(&accH[base + 0], qx);
        atomicAdd(&accH[base + 1], qy);
        atomicAdd(&accH[base + 2], qz);
      }
    }
  }
}

extern "C" void kernel_launch(void* const* d_in, const int* in_sizes, int n_in,
                              void* d_out, int out_size, void* d_ws, size_t ws_size,
                              hipStream_t stream) {
  // input order per setup_inputs(): N, C, O, CB, H, gaussian_weights, hb_min, hb_max
  const float* cO  = (const float*)d_in[2];
  const float* cCB = (const float*)d_in[3];
  const float* cH  = (const float*)d_in[4];
  const float* gw  = (const float*)d_in[5];
  const float* hmn = (const float*)d_in[6];
  const float* hmx = (const float*)d_in[7];
  float* out = (float*)d_out;

  // accs_N and accs_C are exactly zero (K_ANG_HB_GEN == 0); atomics need zeroed
  // accumulators -> zero the whole output every call (deterministic).
  hipMemsetAsync(out, 0, (size_t)out_size * sizeof(float), stream);

  const int ncol = NRES * NTILES * 2;   // 3000
  const int nrow = NRES * NTILES;       // 1500
  force_kernel<<<dim3(ncol + nrow), dim3(64), 0, stream>>>(
      cO, cCB, cH, gw, hmn, hmx, out);
}

// Round 2
// 52.062 us; speedup vs baseline: 1.3155x; 1.3155x over previous
//
#include <hip/hip_runtime.h>

#define NRES  300
#define NTRJ  20
#define NBINS 34
#define PLANE (NTRJ * NRES * 3)   // 18000 floats per output tensor

__device__ __forceinline__ float wred(float v) {
#pragma unroll
  for (int m = 32; m; m >>= 1) v += __shfl_xor(v, m, 64);
  return v;
}

__global__ __launch_bounds__(256)
void force_kernel(const float* __restrict__ cO,
                  const float* __restrict__ cCB,
                  const float* __restrict__ cH,
                  const float* __restrict__ gw,
                  const float* __restrict__ hmin,
                  const float* __restrict__ hmax,
                  float* __restrict__ out) {
  float* accO  = out + 2 * PLANE;
  float* accCB = out + 3 * PLANE;
  float* accH  = out + 4 * PLANE;
  const int tid   = threadIdx.x;
  const int wv_id = tid >> 6;        // wave within block: 0..3
  const int lane  = tid & 63;
  const int bx    = blockIdx.x;

  if (bx < 1500) {
    // ================= column part: fixed j, lanes over i ==================
    // block owns (j, i-tile of 64); wave w handles trajectories [5w, 5w+5)
    __shared__ float wlds[64 * NBINS];
    const int j  = bx % NRES;
    const int it = bx / NRES;        // 0..4
    const int i  = it * 64 + lane;
    const bool valid = (i < NRES);
    const int ic = valid ? i : NRES - 1;

    // cooperative coalesced load of gw[i-tile, j, :] into LDS [il][k]
    for (int e = tid; e < 64 * NBINS; e += 256) {
      int il = e / NBINS, k = e - il * NBINS;
      int ig = it * 64 + il; if (ig > NRES - 1) ig = NRES - 1;
      wlds[e] = gw[((size_t)ig * NRES + j) * NBINS + k];
    }
    __syncthreads();

    // LDS -> registers (ds_read_b64; stride-34 lanes = 2-way aliasing, free)
    float w[NBINS];
    const float2* p2 = (const float2*)(wlds + lane * NBINS);
#pragma unroll
    for (int k = 0; k < 17; ++k) { float2 v = p2[k]; w[2*k] = v.x; w[2*k+1] = v.y; }

    const float hmn = hmin[(size_t)ic * NRES + j];
    const float hmx = hmax[(size_t)ic * NRES + j];

    for (int b = wv_id * 5; b < wv_id * 5 + 5; ++b) {
      // ---- CB distogram force via 3-segment gaussian recurrence ----
      const float* pi = cCB + ((size_t)b * NRES + ic) * 3;
      const float* pj = cCB + ((size_t)b * NRES + j) * 3;
      float dx = pj[0] - pi[0], dy = pj[1] - pi[1], dz = pj[2] - pi[2];
      float d2 = fmaf(dx, dx, fmaf(dy, dy, dz * dz));
      d2 = fminf(fmaxf(d2, 0.01f), 1600.0f);   // clamp d to [0.1, 40]
      float rinv = __frsqrt_rn(d2);            // 1/d
      float d    = d2 * rinv;                  // d

      // g_k = exp(-0.32*dfm_k^2); g_{k+1} = g_k * m_k; m_{k+1} = m_k * exp(-0.16)
      // anchored at k = 0, 12, 24 (3 independent ILP chains, underflow-safe)
      float dA = d - 3.75f, dB = d - 9.75f, dC = d - 15.75f;
      float gA = __expf(-0.32f * dA * dA), mA = __expf(fmaf(0.32f, dA, -0.08f));
      float gB = __expf(-0.32f * dB * dB), mB = __expf(fmaf(0.32f, dB, -0.08f));
      float gC = __expf(-0.32f * dC * dC), mC = __expf(fmaf(0.32f, dC, -0.08f));
      float s0 = 0.f, s1 = 0.f, s2 = 0.f;
#pragma unroll
      for (int k = 0; k < 10; ++k) {
        s0 = fmaf(w[k]      * dA, gA, s0); gA *= mA; mA *= 0.85214379f; dA -= 0.5f;
        s1 = fmaf(w[k + 12] * dB, gB, s1); gB *= mB; mB *= 0.85214379f; dB -= 0.5f;
        s2 = fmaf(w[k + 24] * dC, gC, s2); gC *= mC; mC *= 0.85214379f; dC -= 0.5f;
      }
      s0 = fmaf(w[10] * dA, gA, s0); gA *= mA; dA -= 0.5f;
      s1 = fmaf(w[22] * dB, gB, s1); gB *= mB; dB -= 0.5f;
      s0 = fmaf(w[11] * dA, gA, s0);
      s1 = fmaf(w[23] * dB, gB, s1);
      float s  = (s0 + s1) + s2;
      float cf = 76.8f * s * rinv;             // K/sigma^3 = 150/1.953125
      float px = cf * dx, py = cf * dy, pz = cf * dz;

      // ---- HB min/max restraint (O_j - H_i), column sums -> accs_O ----
      const float* ph = cH + ((size_t)b * NRES + ic) * 3;
      const float* po = cO + ((size_t)b * NRES + j) * 3;
      float ex = po[0] - ph[0], ey = po[1] - ph[1], ez = po[2] - ph[2];
      float e2 = fmaf(ex, ex, fmaf(ey, ey, ez * ez));
      e2 = fminf(fmaxf(e2, 0.01f), 1600.0f);
      float rh = __frsqrt_rn(e2);
      float dh = e2 * rh;
      float vmin = fmaxf(hmn - dh, 0.0f);
      float vmax = fmaxf(dh - hmx, 0.0f);
      float fmn = 15.0f * vmin;                               // 3*5*v^1
      float fmx = (vmax > 0.0f) ? 5.0f * __powf(vmax, 0.75f) : 0.0f;
      float ff = (fmn - fmx) * rh;
      float qx = ff * ex, qy = ff * ey, qz = ff * ez;

      if (!valid) { px = py = pz = qx = qy = qz = 0.0f; }

      px = wred(px); py = wred(py); pz = wred(pz);
      qx = wred(qx); qy = wred(qy); qz = wred(qz);
      if (lane == 0) {
        int base = (b * NRES + j) * 3;
        atomicAdd(&accCB[base + 0], px);
        atomicAdd(&accCB[base + 1], py);
        atomicAdd(&accCB[base + 2], pz);
        atomicAdd(&accO[base + 0], qx);
        atomicAdd(&accO[base + 1], qy);
        atomicAdd(&accO[base + 2], qz);
      }
    }
  } else {
    // ================= row part: fixed i, lanes over j -> accs_H ===========
    const int unit = (bx - 1500) * 4 + wv_id;   // 0..1499
    const int i  = unit % NRES;
    const int jt = unit / NRES;                 // 0..4
    const int jj = jt * 64 + lane;
    const bool valid = (jj < NRES);
    const int jc = valid ? jj : NRES - 1;

    const float hmn = hmin[(size_t)i * NRES + jc];
    const float hmx = hmax[(size_t)i * NRES + jc];

    for (int b = 0; b < NTRJ; ++b) {
      const float* ph = cH + ((size_t)b * NRES + i) * 3;
      const float* po = cO + ((size_t)b * NRES + jc) * 3;
      float ex = po[0] - ph[0], ey = po[1] - ph[1], ez = po[2] - ph[2];
      float e2 = fmaf(ex, ex, fmaf(ey, ey, ez * ez));
      e2 = fminf(fmaxf(e2, 0.01f), 1600.0f);
      float rh = __frsqrt_rn(e2);
      float dh = e2 * rh;
      float vmin = fmaxf(hmn - dh, 0.0f);
      float vmax = fmaxf(dh - hmx, 0.0f);
      float fmn = 15.0f * vmin;
      float fmx = (vmax > 0.0f) ? 5.0f * __powf(vmax, 0.75f) : 0.0f;
      float ff = (fmn - fmx) * rh;
      float qx = -ff * ex, qy = -ff * ey, qz = -ff * ez;

      if (!valid) { qx = qy = qz = 0.0f; }

      qx = wred(qx); qy = wred(qy); qz = wred(qz);
      if (lane == 0) {
        int base = (b * NRES + i) * 3;
        atomicAdd(&accH[base + 0], qx);
        atomicAdd(&accH[base + 1], qy);
        atomicAdd(&accH[base + 2], qz);
      }
    }
  }
}

extern "C" void kernel_launch(void* const* d_in, const int* in_sizes, int n_in,
                              void* d_out, int out_size, void* d_ws, size_t ws_size,
                              hipStream_t stream) {
  // input order per setup_inputs(): N, C, O, CB, H, gaussian_weights, hb_min, hb_max
  const float* cO  = (const float*)d_in[2];
  const float* cCB = (const float*)d_in[3];
  const float* cH  = (const float*)d_in[4];
  const float* gw  = (const float*)d_in[5];
  const float* hmn = (const float*)d_in[6];
  const float* hmx = (const float*)d_in[7];
  float* out = (float*)d_out;

  // accs_N and accs_C are exactly zero (K_ANG_HB_GEN == 0); atomics need zeroed
  // accumulators -> zero the whole output every call (deterministic).
  hipMemsetAsync(out, 0, (size_t)out_size * sizeof(float), stream);

  // 1500 column blocks (300 j x 5 i-tiles, 4 waves = 20 trajs each)
  // + 375 row blocks (4 row-units each)
  force_kernel<<<dim3(1500 + 375), dim3(256), 0, stream>>>(
      cO, cCB, cH, gw, hmn, hmx, out);
}